// Round 4
// baseline (388.555 us; speedup 1.0000x reference)
//
#include <hip/hip_runtime.h>
#include <hip/hip_bf16.h>

// CapsuleLayer dynamic routing, MI355X.
// B=32,N=2048,D=32 inputs; C=64,V=32 output caps; 3 routing rounds.
// u_hat computed once via bf16 MFMA -> ws (bf16 [n][b][p], 256MB);
// each routing round = one fused pass over u_hat (agree -> softmax -> s-accum),
// using linearity of agreement: b_logits = u_hat . (v1+v2+...).
// Round 4 change: uhat rebuilt for memory-level parallelism. Wave-per-n,
// 16 batches x 8 p-tiles, 16 dwordx4 loads issued per batch before use
// (~256B/wave in flight), no LDS staging / no lgkmcnt serialization, direct
// 2B stores (merge to full lines under the [n][b][p] layout). Routing rounds
// get a 1-deep load pipeline.

#define B_ 32
#define N_ 2048
#define D_ 32
#define C_ 64
#define V_ 32

typedef __attribute__((ext_vector_type(4))) float f32x4;
typedef __attribute__((ext_vector_type(4))) int i32x4;
typedef __bf16 bf16x8 __attribute__((ext_vector_type(8)));

__device__ __forceinline__ unsigned f2bf1(float f) {
  unsigned u = __builtin_bit_cast(unsigned, f);
  return (u + 0x7FFFu + ((u >> 16) & 1u)) >> 16;  // RNE
}
__device__ __forceinline__ float bf2f(unsigned h) {
  unsigned u = h << 16;
  return __builtin_bit_cast(float, u);
}

// u_hat[n][b][p] (p=c*32+v), bf16. Wave-per-n: block = 4 waves = 4 n.
// Per batch: 16 dwordx4 W loads in flight, then 8x{convert, 2 MFMA, 8 stores}.
__global__ __launch_bounds__(256) void uhat_kernel(const float* __restrict__ x,
                                                   const float* __restrict__ W,
                                                   unsigned short* __restrict__ uh) {
  const int n = blockIdx.x * 4 + (threadIdx.x >> 6);
  const int l = threadIdx.x & 63;
  const int l16 = l & 15, kg = l >> 4;  // A/B frag: row/col = l16, k = kg*8 + i

  bf16x8 a[2];
#pragma unroll
  for (int mt = 0; mt < 2; ++mt) {
    const float* xp = x + (((size_t)(mt * 16 + l16)) * N_ + n) * D_ + kg * 8;
    f32x4 x0 = *(const f32x4*)xp;
    f32x4 x1 = *(const f32x4*)(xp + 4);
    i32x4 af;
    af[0] = f2bf1(x0[0]) | (f2bf1(x0[1]) << 16);
    af[1] = f2bf1(x0[2]) | (f2bf1(x0[3]) << 16);
    af[2] = f2bf1(x1[0]) | (f2bf1(x1[1]) << 16);
    af[3] = f2bf1(x1[2]) | (f2bf1(x1[3]) << 16);
    a[mt] = __builtin_bit_cast(bf16x8, af);
  }
  const f32x4 zero = {0.f, 0.f, 0.f, 0.f};
  const float* wbase = W + ((size_t)n * 2048 + l16) * D_ + kg * 8;
  unsigned short* ubase = uh + (size_t)n * 32 * 2048 + l16;

  for (int bt = 0; bt < 16; ++bt) {
    // issue the whole batch's loads first: 16 x 16B in flight
    f32x4 w[16];
    const float* wb = wbase + (size_t)(bt * 128) * D_;
#pragma unroll
    for (int t = 0; t < 8; ++t) {
      w[2 * t] = *(const f32x4*)(wb + (size_t)(t * 16) * D_);
      w[2 * t + 1] = *(const f32x4*)(wb + (size_t)(t * 16) * D_ + 4);
    }
#pragma unroll
    for (int t = 0; t < 8; ++t) {
      f32x4 w0 = w[2 * t], w1 = w[2 * t + 1];
      i32x4 bv;
      bv[0] = f2bf1(w0[0]) | (f2bf1(w0[1]) << 16);
      bv[1] = f2bf1(w0[2]) | (f2bf1(w0[3]) << 16);
      bv[2] = f2bf1(w1[0]) | (f2bf1(w1[1]) << 16);
      bv[3] = f2bf1(w1[2]) | (f2bf1(w1[3]) << 16);
      bf16x8 bfrag = __builtin_bit_cast(bf16x8, bv);
#pragma unroll
      for (int mt = 0; mt < 2; ++mt) {
        f32x4 acc = __builtin_amdgcn_mfma_f32_16x16x32_bf16(a[mt], bfrag, zero, 0, 0, 0);
#pragma unroll
        for (int j = 0; j < 4; ++j) {
          const int br = mt * 16 + kg * 4 + j;  // C/D: row=(l>>4)*4+j, col=l&15
          ubase[(size_t)br * 2048 + bt * 128 + t * 16] = (unsigned short)f2bf1(acc[j]);
        }
      }
    }
  }
}

// Routing pass: s[b,c,v] = sum_n softmax_c(u_hat[b,n,:,:].vsum[b,:,:])[c] * u_hat[b,n,c,v]
// wave lane l == c. Block = 4 waves x 16 n, same b. 1-deep load pipeline.
template <int ROUND>
__global__ __launch_bounds__(256) void routing_kernel(const unsigned short* __restrict__ uh,
                                                      const float* __restrict__ vsum,
                                                      float* __restrict__ part) {
  const int b = blockIdx.x >> 5;  // 32 chunks per b
  const int chunk = blockIdx.x & 31;
  const int wave = threadIdx.x >> 6;
  const int l = threadIdx.x & 63;  // = c

  float vs[32];
  if (ROUND >= 2) {
    const f32x4* vp = (const f32x4*)(vsum + ((size_t)b * 64 + l) * 32);
#pragma unroll
    for (int i = 0; i < 8; ++i) {
      f32x4 t = vp[i];
      vs[4 * i] = t[0]; vs[4 * i + 1] = t[1]; vs[4 * i + 2] = t[2]; vs[4 * i + 3] = t[3];
    }
  }
  float sacc[32];
#pragma unroll
  for (int v = 0; v < 32; ++v) sacc[v] = 0.f;

  const int n0 = chunk * 64 + wave * 16;
  const unsigned short* ub = uh + ((size_t)n0 * 32 + b) * 2048 + l * 32;
  const size_t nstride = (size_t)32 * 2048;  // shorts per n

  i32x4 qA0 = ((const i32x4*)ub)[0], qA1 = ((const i32x4*)ub)[1],
        qA2 = ((const i32x4*)ub)[2], qA3 = ((const i32x4*)ub)[3];

  for (int ni = 0; ni < 16; ++ni) {
    i32x4 qB0, qB1, qB2, qB3;
    if (ni < 15) {
      const i32x4* nx = (const i32x4*)(ub + (size_t)(ni + 1) * nstride);
      qB0 = nx[0]; qB1 = nx[1]; qB2 = nx[2]; qB3 = nx[3];
    }
    float u[32];
#pragma unroll
    for (int i = 0; i < 4; ++i) {
      unsigned v0 = (unsigned)qA0[i], v1 = (unsigned)qA1[i], v2 = (unsigned)qA2[i], v3 = (unsigned)qA3[i];
      u[0 + 2 * i] = bf2f(v0 & 0xffffu);  u[0 + 2 * i + 1] = bf2f(v0 >> 16);
      u[8 + 2 * i] = bf2f(v1 & 0xffffu);  u[8 + 2 * i + 1] = bf2f(v1 >> 16);
      u[16 + 2 * i] = bf2f(v2 & 0xffffu); u[16 + 2 * i + 1] = bf2f(v2 >> 16);
      u[24 + 2 * i] = bf2f(v3 & 0xffffu); u[24 + 2 * i + 1] = bf2f(v3 >> 16);
    }
    float r;
    if (ROUND >= 2) {
      float br = 0.f;
#pragma unroll
      for (int v = 0; v < 32; ++v) br = fmaf(u[v], vs[v], br);
      float m = br;
#pragma unroll
      for (int off = 32; off; off >>= 1) m = fmaxf(m, __shfl_xor(m, off, 64));
      float e = __expf(br - m);
      float den = e;
#pragma unroll
      for (int off = 32; off; off >>= 1) den += __shfl_xor(den, off, 64);
      r = e / den;
    } else {
      r = 1.0f / 64.0f;  // softmax of zeros
    }
#pragma unroll
    for (int v = 0; v < 32; ++v) sacc[v] = fmaf(r, u[v], sacc[v]);
    qA0 = qB0; qA1 = qB1; qA2 = qB2; qA3 = qB3;
  }

  __shared__ float red[4][64][33];  // +1 pad: conflict-free
#pragma unroll
  for (int v = 0; v < 32; ++v) red[wave][l][v] = sacc[v];
  __syncthreads();
  const int t = threadIdx.x;
  f32x4 o0, o1;
#pragma unroll
  for (int i = 0; i < 4; ++i) {
    const int e0 = t * 8 + i, e1 = t * 8 + 4 + i;
    o0[i] = red[0][e0 >> 5][e0 & 31] + red[1][e0 >> 5][e0 & 31] +
            red[2][e0 >> 5][e0 & 31] + red[3][e0 >> 5][e0 & 31];
    o1[i] = red[0][e1 >> 5][e1 & 31] + red[1][e1 >> 5][e1 & 31] +
            red[2][e1 >> 5][e1 & 31] + red[3][e1 >> 5][e1 & 31];
  }
  float* pp = part + ((size_t)blockIdx.x) * 2048 + t * 8;
  *(f32x4*)pp = o0;
  *(f32x4*)(pp + 4) = o1;
}

// Reduce partials -> s, squash -> v. Writes v to out; maintains vsum for agreement.
template <int ROUND>
__global__ __launch_bounds__(256) void squash_kernel(const float* __restrict__ part,
                                                     float* __restrict__ vsum,
                                                     float* __restrict__ out) {
  const int t = blockIdx.x * 256 + threadIdx.x;  // 0..65535 = b*2048 + c*32 + v
  const int b = t >> 11;
  const int e = t & 2047;
  float sv = 0.f;
#pragma unroll
  for (int k = 0; k < 32; ++k) sv += part[((size_t)(b * 32 + k)) * 2048 + e];
  float sq = sv * sv;
#pragma unroll
  for (int off = 16; off; off >>= 1) sq += __shfl_xor(sq, off, 64);  // sum over v (32-lane groups)
  float scale = (sq / (1.f + sq)) * rsqrtf(sq + 1e-9f);
  float val = sv * scale;
  out[t] = val;
  if (ROUND == 1) vsum[t] = val;
  else if (ROUND == 2) vsum[t] += val;
}

extern "C" void kernel_launch(void* const* d_in, const int* in_sizes, int n_in,
                              void* d_out, int out_size, void* d_ws, size_t ws_size,
                              hipStream_t stream) {
  const float* x = (const float*)d_in[0];  // [B,N,D]
  const float* W = (const float*)d_in[1];  // [1,N,C,V,D]
  float* out = (float*)d_out;              // [B,1,C,V,1] = 65536 fp32

  const size_t UH_BYTES = (size_t)B_ * N_ * C_ * V_ * 2;  // 268435456
  const size_t PART_BYTES = (size_t)B_ * 32 * 2048 * 4;   // 8388608
  const size_t VSUM_BYTES = (size_t)B_ * C_ * V_ * 4;     // 262144
  if (ws_size < UH_BYTES + PART_BYTES + VSUM_BYTES) return;  // can't run

  unsigned short* uh = (unsigned short*)d_ws;
  float* part = (float*)((char*)d_ws + UH_BYTES);
  float* vsum = (float*)((char*)d_ws + UH_BYTES + PART_BYTES);

  uhat_kernel<<<N_ / 4, 256, 0, stream>>>(x, W, uh);
  routing_kernel<1><<<B_ * 32, 256, 0, stream>>>(uh, vsum, part);
  squash_kernel<1><<<256, 256, 0, stream>>>(part, vsum, out);
  routing_kernel<2><<<B_ * 32, 256, 0, stream>>>(uh, vsum, part);
  squash_kernel<2><<<256, 256, 0, stream>>>(part, vsum, out);
  routing_kernel<3><<<B_ * 32, 256, 0, stream>>>(uh, vsum, part);
  squash_kernel<3><<<256, 256, 0, stream>>>(part, vsum, out);
}

// Round 5
// 330.706 us; speedup vs baseline: 1.1749x; 1.1749x over previous
//
#include <hip/hip_runtime.h>
#include <hip/hip_bf16.h>

// CapsuleLayer dynamic routing, MI355X.
// B=32,N=2048,D=32 inputs; C=64,V=32 output caps; 3 routing rounds.
// u_hat computed once via bf16 MFMA -> ws (bf16 [n][b][p], 256MB);
// each routing round = one fused pass over u_hat (agree -> softmax -> s-accum),
// using linearity of agreement: b_logits = u_hat . (v1+v2+...).
// Round 5: back to r3's LDS-transpose store path (r4's per-element stores
// regressed: 1024 store-instr/wave ate issue BW + vmcnt slots). Fix r3's
// serialization instead: per-phase W prefetch (next phase's 8 dwordx4 issued
// before current phase's MFMA+flush) + double-buffered LDS tile (one lgkmcnt
// fence per phase instead of two).

#define B_ 32
#define N_ 2048
#define D_ 32
#define C_ 64
#define V_ 32

typedef __attribute__((ext_vector_type(4))) float f32x4;
typedef __attribute__((ext_vector_type(4))) int i32x4;
typedef __bf16 bf16x8 __attribute__((ext_vector_type(8)));

__device__ __forceinline__ unsigned f2bf1(float f) {
  unsigned u = __builtin_bit_cast(unsigned, f);
  return (u + 0x7FFFu + ((u >> 16) & 1u)) >> 16;  // RNE
}
__device__ __forceinline__ float bf2f(unsigned h) {
  unsigned u = h << 16;
  return __builtin_bit_cast(float, u);
}

// u_hat[n][b][p] (p=c*32+v), bf16. Block = one n, 4 waves; wave owns 512 p.
// 8 phases x 64 p: prefetch(ph+1) -> MFMA(ph) -> LDS buf[ph&1] -> lgkm fence
// -> dwordx4 flush. Row stride 68 shorts: kg write groups 8 banks apart.
__global__ __launch_bounds__(256) void uhat_kernel(const float* __restrict__ x,
                                                   const float* __restrict__ W,
                                                   unsigned short* __restrict__ uh) {
  const int n = blockIdx.x;
  const int wave = threadIdx.x >> 6;
  const int l = threadIdx.x & 63;
  const int l16 = l & 15, kg = l >> 4;  // A/B frag: row/col = l16, k = kg*8 + i

  __shared__ unsigned short lds[2][4][32 * 68];

  bf16x8 a[2];
#pragma unroll
  for (int mt = 0; mt < 2; ++mt) {
    const float* xp = x + (((size_t)(mt * 16 + l16)) * N_ + n) * D_ + kg * 8;
    f32x4 x0 = *(const f32x4*)xp;
    f32x4 x1 = *(const f32x4*)(xp + 4);
    i32x4 af;
    af[0] = f2bf1(x0[0]) | (f2bf1(x0[1]) << 16);
    af[1] = f2bf1(x0[2]) | (f2bf1(x0[3]) << 16);
    af[2] = f2bf1(x1[0]) | (f2bf1(x1[1]) << 16);
    af[3] = f2bf1(x1[2]) | (f2bf1(x1[3]) << 16);
    a[mt] = __builtin_bit_cast(bf16x8, af);
  }
  const f32x4 zero = {0.f, 0.f, 0.f, 0.f};
  const int br_f = l >> 1, half = l & 1;  // flush roles: 2 lanes per b-row
  // Wave's W window: rows p = wave*512 + ph*64 + pt4*16 + l16, floats kg*8..
  const float* wbase = W + ((size_t)n * 2048 + wave * 512 + l16) * D_ + kg * 8;

  // prologue: load phase 0 into wreg
  f32x4 wreg[8];
#pragma unroll
  for (int pt4 = 0; pt4 < 4; ++pt4) {
    const float* wp = wbase + (size_t)(pt4 * 16) * D_;
    wreg[2 * pt4] = *(const f32x4*)wp;
    wreg[2 * pt4 + 1] = *(const f32x4*)(wp + 4);
  }

#pragma unroll
  for (int ph = 0; ph < 8; ++ph) {
    unsigned short* wlds = lds[ph & 1][wave];
    // issue next phase's loads first: in flight across this phase's MFMA+flush
    f32x4 wnext[8];
    if (ph < 7) {
#pragma unroll
      for (int pt4 = 0; pt4 < 4; ++pt4) {
        const float* wp = wbase + (size_t)((ph + 1) * 64 + pt4 * 16) * D_;
        wnext[2 * pt4] = *(const f32x4*)wp;
        wnext[2 * pt4 + 1] = *(const f32x4*)(wp + 4);
      }
      __builtin_amdgcn_sched_barrier(0);  // pin load issue above compute
    }
    // compute phase ph from wreg
#pragma unroll
    for (int pt4 = 0; pt4 < 4; ++pt4) {
      f32x4 w0 = wreg[2 * pt4], w1 = wreg[2 * pt4 + 1];
      i32x4 bv;
      bv[0] = f2bf1(w0[0]) | (f2bf1(w0[1]) << 16);
      bv[1] = f2bf1(w0[2]) | (f2bf1(w0[3]) << 16);
      bv[2] = f2bf1(w1[0]) | (f2bf1(w1[1]) << 16);
      bv[3] = f2bf1(w1[2]) | (f2bf1(w1[3]) << 16);
      bf16x8 bfrag = __builtin_bit_cast(bf16x8, bv);
#pragma unroll
      for (int mt = 0; mt < 2; ++mt) {
        f32x4 acc = __builtin_amdgcn_mfma_f32_16x16x32_bf16(a[mt], bfrag, zero, 0, 0, 0);
#pragma unroll
        for (int j = 0; j < 4; ++j) {
          const int br = mt * 16 + kg * 4 + j;  // C/D: row=(l>>4)*4+j, col=l&15
          wlds[br * 68 + pt4 * 16 + l16] = (unsigned short)f2bf1(acc[j]);
        }
      }
    }
    // this phase's LDS writes complete before cross-lane readback
    asm volatile("s_waitcnt lgkmcnt(0)" ::: "memory");
    __builtin_amdgcn_sched_barrier(0);
    {
      const unsigned short* src = wlds + br_f * 68 + half * 32;
      unsigned short* dst = uh + ((size_t)n * 32 + br_f) * 2048 +
                            (size_t)(wave * 512 + ph * 64 + half * 32);
      i32x4 v0 = *(const i32x4*)(src + 0);
      i32x4 v1 = *(const i32x4*)(src + 8);
      i32x4 v2 = *(const i32x4*)(src + 16);
      i32x4 v3 = *(const i32x4*)(src + 24);
      *(i32x4*)(dst + 0) = v0;
      *(i32x4*)(dst + 8) = v1;
      *(i32x4*)(dst + 16) = v2;
      *(i32x4*)(dst + 24) = v3;
    }
    __builtin_amdgcn_sched_barrier(0);  // keep flush ahead of next phase body
    if (ph < 7) {
#pragma unroll
      for (int i = 0; i < 8; ++i) wreg[i] = wnext[i];
    }
  }
}

// Routing pass: s[b,c,v] = sum_n softmax_c(u_hat[b,n,:,:].vsum[b,:,:])[c] * u_hat[b,n,c,v]
// wave lane l == c. Block = 4 waves x 16 n, same b. Partials (no atomics) to ws.
template <int ROUND>
__global__ __launch_bounds__(256) void routing_kernel(const unsigned short* __restrict__ uh,
                                                      const float* __restrict__ vsum,
                                                      float* __restrict__ part) {
  const int b = blockIdx.x >> 5;  // 32 chunks per b
  const int chunk = blockIdx.x & 31;
  const int wave = threadIdx.x >> 6;
  const int l = threadIdx.x & 63;  // = c

  float vs[32];
  if (ROUND >= 2) {
    const f32x4* vp = (const f32x4*)(vsum + ((size_t)b * 64 + l) * 32);
#pragma unroll
    for (int i = 0; i < 8; ++i) {
      f32x4 t = vp[i];
      vs[4 * i] = t[0]; vs[4 * i + 1] = t[1]; vs[4 * i + 2] = t[2]; vs[4 * i + 3] = t[3];
    }
  }
  float sacc[32];
#pragma unroll
  for (int v = 0; v < 32; ++v) sacc[v] = 0.f;

  const int n0 = chunk * 64 + wave * 16;
  for (int ni = 0; ni < 16; ++ni) {
    const int n = n0 + ni;
    const i32x4* up = (const i32x4*)(uh + ((size_t)n * 32 + b) * 2048 + l * 32);
    i32x4 qs0 = up[0], qs1 = up[1], qs2 = up[2], qs3 = up[3];
    float u[32];
#pragma unroll
    for (int i = 0; i < 4; ++i) {
      unsigned v0 = (unsigned)qs0[i], v1 = (unsigned)qs1[i], v2 = (unsigned)qs2[i], v3 = (unsigned)qs3[i];
      u[0 + 2 * i] = bf2f(v0 & 0xffffu);  u[0 + 2 * i + 1] = bf2f(v0 >> 16);
      u[8 + 2 * i] = bf2f(v1 & 0xffffu);  u[8 + 2 * i + 1] = bf2f(v1 >> 16);
      u[16 + 2 * i] = bf2f(v2 & 0xffffu); u[16 + 2 * i + 1] = bf2f(v2 >> 16);
      u[24 + 2 * i] = bf2f(v3 & 0xffffu); u[24 + 2 * i + 1] = bf2f(v3 >> 16);
    }
    float r;
    if (ROUND >= 2) {
      float br = 0.f;
#pragma unroll
      for (int v = 0; v < 32; ++v) br = fmaf(u[v], vs[v], br);
      float m = br;
#pragma unroll
      for (int off = 32; off; off >>= 1) m = fmaxf(m, __shfl_xor(m, off, 64));
      float e = __expf(br - m);
      float den = e;
#pragma unroll
      for (int off = 32; off; off >>= 1) den += __shfl_xor(den, off, 64);
      r = e / den;
    } else {
      r = 1.0f / 64.0f;  // softmax of zeros
    }
#pragma unroll
    for (int v = 0; v < 32; ++v) sacc[v] = fmaf(r, u[v], sacc[v]);
  }

  __shared__ float red[4][64][33];  // +1 pad: conflict-free
#pragma unroll
  for (int v = 0; v < 32; ++v) red[wave][l][v] = sacc[v];
  __syncthreads();
  const int t = threadIdx.x;
  f32x4 o0, o1;
#pragma unroll
  for (int i = 0; i < 4; ++i) {
    const int e0 = t * 8 + i, e1 = t * 8 + 4 + i;
    o0[i] = red[0][e0 >> 5][e0 & 31] + red[1][e0 >> 5][e0 & 31] +
            red[2][e0 >> 5][e0 & 31] + red[3][e0 >> 5][e0 & 31];
    o1[i] = red[0][e1 >> 5][e1 & 31] + red[1][e1 >> 5][e1 & 31] +
            red[2][e1 >> 5][e1 & 31] + red[3][e1 >> 5][e1 & 31];
  }
  float* pp = part + ((size_t)blockIdx.x) * 2048 + t * 8;
  *(f32x4*)pp = o0;
  *(f32x4*)(pp + 4) = o1;
}

// Reduce partials -> s, squash -> v. Writes v to out; maintains vsum for agreement.
template <int ROUND>
__global__ __launch_bounds__(256) void squash_kernel(const float* __restrict__ part,
                                                     float* __restrict__ vsum,
                                                     float* __restrict__ out) {
  const int t = blockIdx.x * 256 + threadIdx.x;  // 0..65535 = b*2048 + c*32 + v
  const int b = t >> 11;
  const int e = t & 2047;
  float sv = 0.f;
#pragma unroll
  for (int k = 0; k < 32; ++k) sv += part[((size_t)(b * 32 + k)) * 2048 + e];
  float sq = sv * sv;
#pragma unroll
  for (int off = 16; off; off >>= 1) sq += __shfl_xor(sq, off, 64);  // sum over v (32-lane groups)
  float scale = (sq / (1.f + sq)) * rsqrtf(sq + 1e-9f);
  float val = sv * scale;
  out[t] = val;
  if (ROUND == 1) vsum[t] = val;
  else if (ROUND == 2) vsum[t] += val;
}

extern "C" void kernel_launch(void* const* d_in, const int* in_sizes, int n_in,
                              void* d_out, int out_size, void* d_ws, size_t ws_size,
                              hipStream_t stream) {
  const float* x = (const float*)d_in[0];  // [B,N,D]
  const float* W = (const float*)d_in[1];  // [1,N,C,V,D]
  float* out = (float*)d_out;              // [B,1,C,V,1] = 65536 fp32

  const size_t UH_BYTES = (size_t)B_ * N_ * C_ * V_ * 2;  // 268435456
  const size_t PART_BYTES = (size_t)B_ * 32 * 2048 * 4;   // 8388608
  const size_t VSUM_BYTES = (size_t)B_ * C_ * V_ * 4;     // 262144
  if (ws_size < UH_BYTES + PART_BYTES + VSUM_BYTES) return;  // can't run

  unsigned short* uh = (unsigned short*)d_ws;
  float* part = (float*)((char*)d_ws + UH_BYTES);
  float* vsum = (float*)((char*)d_ws + UH_BYTES + PART_BYTES);

  uhat_kernel<<<N_, 256, 0, stream>>>(x, W, uh);
  routing_kernel<1><<<B_ * 32, 256, 0, stream>>>(uh, vsum, part);
  squash_kernel<1><<<256, 256, 0, stream>>>(part, vsum, out);
  routing_kernel<2><<<B_ * 32, 256, 0, stream>>>(uh, vsum, part);
  squash_kernel<2><<<256, 256, 0, stream>>>(part, vsum, out);
  routing_kernel<3><<<B_ * 32, 256, 0, stream>>>(uh, vsum, part);
  squash_kernel<3><<<256, 256, 0, stream>>>(part, vsum, out);
}